// Round 4
// baseline (139.922 us; speedup 1.0000x reference)
//
#include <hip/hip_runtime.h>
#include <hip/hip_bf16.h>
#include <stdint.h>

// KGEdges round 17 — 2 dispatches: BK=64 projc (R16, unchanged), d-blocked edge.
// R16 post-mortem: barrier-halving in projc gave only -0.18 us -> projc is near
// its floor (~3 us). Budget at 99.44: ~85 us mandatory ws-poison fills (their own
// 80%-HBM roofline) + ~14.4 us controllable; edge ~4.5 us vs 3.4 us trans-pipe
// floor (1024 v_rcp/thread x 4cyc, 2 waves/SIMD). The ~1 us gap == exposed
// up-front 64 KB/block LDS staging (128 KB/CU / ~135 GB/s-per-CU L2 ~= 0.95 us).
// R17: stage d in 4 chunks of 64, double-buffered — chunk 0 exposed (~0.25 us),
// chunks 1-3 hidden under trans-bound compute. Per-output d-order identical ->
// bit-identical outputs. LDS 68->35 KB.
// Semantics (R8-R16 green, absmax 0.015625): out[b,i,j] = sum_d w_out[d]*
// tanh(head[b,j,d]+child[b,i,d]) + mm_i + mm_j; head=enc@Wh^T+bh, child=enc@Wc^T;
// fp32 in / int32 mask / fp32 out. Exp-domain: sum w*tanh = S + sum(-2w)*
// rcp(Eh*Ec+1), E=exp2(K*x), K=2log2(e).

typedef __bf16 bf16_t;
typedef __attribute__((ext_vector_type(8))) __bf16 bf16x8;
typedef __attribute__((ext_vector_type(4))) float f32x4;
typedef __attribute__((ext_vector_type(4))) uint32_t u32x4;

#define SL 256
#define ENC 1024
#define NTOT 512
#define KSCALE 2.8853900817779268f  // 2*log2(e)
#define DCH 64    // edge d-chunk
#define ESTR 66   // edge LDS row stride (f32): 66 mod 32 = 2 -> 2-way max (free, m136)

__device__ __forceinline__ uint32_t bfpack(float a, float b) {  // 2x f32 -> packed bf16 (RNE)
  uint32_t ua = __float_as_uint(a); ua = ua + 0x7FFFu + ((ua >> 16) & 1u);
  uint32_t ub = __float_as_uint(b); ub = ub + 0x7FFFu + ((ub >> 16) & 1u);
  return (ua >> 16) | (ub & 0xFFFF0000u);
}

// ---- projc: fused convert+proj, register-prefetch pipeline, dbuf LDS, 8 waves.
// hc[s][0:256]=exp2(K*(enc@Wh^T+bh)) [Eh], hc[s][256:512]=exp2(K*enc@Wc^T) [Ec]
// 64x64 tile, BK=64 (16 iters, 1 barrier each), 8 waves each 1x2 sub-tile,
// 4x MFMA 16x16x32 bf16 per iter (bit-proven maps). Unchanged from R16.
__global__ __launch_bounds__(512)
void projc_kernel(const float* __restrict__ enc, const float* __restrict__ Wh,
                  const float* __restrict__ Wc, const float* __restrict__ bh,
                  float* __restrict__ hc) {
  __shared__ bf16_t As[2][4096];   // 64 rows x 64 k, bf16 (8 KB each buf)
  __shared__ bf16_t Bs[2][4096];
  const int t = threadIdx.x;
  const int wv = t >> 6, lane = t & 63;
  const int m0 = blockIdx.x * 64;   // 32 blocks (2048 rows)
  const int n0 = blockIdx.y * 64;   // 8 blocks (512 cols of [head|child])
  const int srow = t >> 3;          // staging row 0..63
  const int sch = (t & 7) * 8;      // fp32 elem offset in row (0/8/.../56)
  const int mq = (wv & 3) * 16;     // wave's 16-row slice of the 64-row tile
  const int nq = (wv >> 2) * 32;    // wave's 32-col slice of the 64-col tile
  const int fr = lane & 15, kq = lane >> 4;

  f32x4 acc0 = {0.f, 0.f, 0.f, 0.f};
  f32x4 acc1 = acc0;

  const float* gA = enc + (size_t)(m0 + srow) * ENC + sch;
  const float* gW = ((n0 < 256) ? Wh + (size_t)(n0 + srow) * ENC
                                : Wc + (size_t)(n0 - 256 + srow) * ENC) + sch;

  // prologue: load k-tile 0 into registers (8 f32 per matrix per thread)
  f32x4 a0 = *(const f32x4*)(gA);
  f32x4 a1 = *(const f32x4*)(gA + 4);
  f32x4 w0 = *(const f32x4*)(gW);
  f32x4 w1 = *(const f32x4*)(gW + 4);

#pragma unroll 2
  for (int i = 0; i < 16; ++i) {
    const int buf = i & 1;
    // issue NEXT tile's loads first — they fly across pack+write+barrier+MFMA
    f32x4 na0, na1, nw0, nw1;
    if (i + 1 < 16) {
      const int k1 = (i + 1) * 64;
      na0 = *(const f32x4*)(gA + k1);
      na1 = *(const f32x4*)(gA + k1 + 4);
      nw0 = *(const f32x4*)(gW + k1);
      nw1 = *(const f32x4*)(gW + k1 + 4);
    } else {
      na0 = a0; na1 = a1; nw0 = w0; nw1 = w1;  // defined values on last iter
    }
    // pack current (vmcnt waits only on the older loads) and stage to LDS
    u32x4 Au = {bfpack(a0[0], a0[1]), bfpack(a0[2], a0[3]),
                bfpack(a1[0], a1[1]), bfpack(a1[2], a1[3])};
    u32x4 Wu = {bfpack(w0[0], w0[1]), bfpack(w0[2], w0[3]),
                bfpack(w1[0], w1[1]), bfpack(w1[2], w1[3])};
    *(u32x4*)&As[buf][t * 8] = Au;   // byte t*16: row srow, k-elems sch.. (linear)
    *(u32x4*)&Bs[buf][t * 8] = Wu;
    __syncthreads();  // publish buf; also fences write(i+1,~buf) from read(i-1,~buf)
    bf16x8 fa0 = *(const bf16x8*)&As[buf][(mq + fr) * 64 + kq * 8];        // k-chunk 0
    bf16x8 fa1 = *(const bf16x8*)&As[buf][(mq + fr) * 64 + 32 + kq * 8];  // k-chunk 1
    bf16x8 fb00 = *(const bf16x8*)&Bs[buf][(nq + fr) * 64 + kq * 8];
    bf16x8 fb01 = *(const bf16x8*)&Bs[buf][(nq + fr) * 64 + 32 + kq * 8];
    bf16x8 fb10 = *(const bf16x8*)&Bs[buf][(nq + 16 + fr) * 64 + kq * 8];
    bf16x8 fb11 = *(const bf16x8*)&Bs[buf][(nq + 16 + fr) * 64 + 32 + kq * 8];
    // k-chunk 0 then k-chunk 1: identical accumulation order to BK=32 version
    acc0 = __builtin_amdgcn_mfma_f32_16x16x32_bf16(fa0, fb00, acc0, 0, 0, 0);
    acc1 = __builtin_amdgcn_mfma_f32_16x16x32_bf16(fa0, fb10, acc1, 0, 0, 0);
    acc0 = __builtin_amdgcn_mfma_f32_16x16x32_bf16(fa1, fb01, acc0, 0, 0, 0);
    acc1 = __builtin_amdgcn_mfma_f32_16x16x32_bf16(fa1, fb11, acc1, 0, 0, 0);
    a0 = na0; a1 = na1; w0 = nw0; w1 = nw1;  // rotate prefetch regs
  }
  // C/D: col=lane&15, row=(lane>>4)*4+r  (bit-proven)
  const int colA = n0 + nq + fr;
  const int colB = colA + 16;
  const float biasA = (colA < 256) ? bh[colA] : 0.0f;
  const float biasB = (colB < 256) ? bh[colB] : 0.0f;
#pragma unroll
  for (int r = 0; r < 4; ++r) {
    int row = m0 + mq + kq * 4 + r;
    hc[(size_t)row * NTOT + colA] = __builtin_amdgcn_exp2f(KSCALE * (acc0[r] + biasA));
    hc[(size_t)row * NTOT + colB] = __builtin_amdgcn_exp2f(KSCALE * (acc1[r] + biasB));
  }
}

// ---- edge: out[b,i,j] = S + sum_d (-2w[d])*rcp(Eh[j,d]*Ec[i,d]+1) + mm_i + mm_j ----
// R17: d-blocked (4 chunks of 64), double-buffered LDS staging hidden under the
// trans-bound compute. Per-output accumulation order identical to R16.
__global__ __launch_bounds__(256)
void edge_kernel(const float* __restrict__ hc, const float* __restrict__ wout,
                 const int* __restrict__ mask, float* __restrict__ out) {
  __shared__ float ldH[2][32 * ESTR];  // 8448 B per buf
  __shared__ float ldC[2][32 * ESTR];
  __shared__ float wS[256];
  __shared__ float red[4];
  const int t = threadIdx.x;
  const int lane = t & 63, wv = t >> 6;
  const int b = blockIdx.z;
  const int i0 = blockIdx.y * 32;
  const int j0 = blockIdx.x * 32;
  const int sbase = b * SL;

  float w = wout[t];
  wS[t] = -2.0f * w;
  float wsum = w;
#pragma unroll
  for (int off = 32; off; off >>= 1) wsum += __shfl_xor(wsum, off);
  if (lane == 0) red[wv] = wsum;

  const float* __restrict__ hbase = &hc[(size_t)(sbase + j0) * NTOT];        // Eh rows
  const float* __restrict__ cbase = &hc[(size_t)(sbase + i0) * NTOT + 256];  // Ec rows

  // stage d-chunk 0 into buf 0: 32 rows x 64 f32 per matrix, 2 f32x4/thread each
#pragma unroll
  for (int u = t; u < 512; u += 256) {
    int row = u >> 4;
    int c4 = (u & 15) << 2;
    *(f32x4*)&ldH[0][row * ESTR + c4] = *(const f32x4*)&hbase[(size_t)row * NTOT + c4];
    *(f32x4*)&ldC[0][row * ESTR + c4] = *(const f32x4*)&cbase[(size_t)row * NTOT + c4];
  }
  __syncthreads();  // covers chunk-0 staging AND red[]/wS
  const float S = (red[0] + red[1]) + (red[2] + red[3]);

  const int tx = t & 15, ty = t >> 4;
  float a00 = 0.f, a01 = 0.f, a10 = 0.f, a11 = 0.f;

  for (int db = 0; db < 4; ++db) {
    const int cur = db & 1;
    if (db < 3) {  // issue next-chunk staging — hides under this chunk's compute
      const int nxt = cur ^ 1;
      const int doff = (db + 1) * DCH;
#pragma unroll
      for (int u = t; u < 512; u += 256) {
        int row = u >> 4;
        int c4 = (u & 15) << 2;
        *(f32x4*)&ldH[nxt][row * ESTR + c4] =
            *(const f32x4*)&hbase[(size_t)row * NTOT + doff + c4];
        *(f32x4*)&ldC[nxt][row * ESTR + c4] =
            *(const f32x4*)&cbase[(size_t)row * NTOT + doff + c4];
      }
    }
    const float* hp0 = &ldH[cur][tx * ESTR];
    const float* hp1 = &ldH[cur][(tx + 16) * ESTR];
    const float* cp0 = &ldC[cur][ty * ESTR];
    const float* cp1 = &ldC[cur][(ty + 16) * ESTR];
    const float* wp = &wS[db * DCH];
#pragma unroll 8
    for (int d = 0; d < DCH; d += 4) {
      f32x4 h0 = *(const f32x4*)&hp0[d];
      f32x4 h1 = *(const f32x4*)&hp1[d];
      f32x4 c0 = *(const f32x4*)&cp0[d];
      f32x4 c1 = *(const f32x4*)&cp1[d];
      f32x4 w4 = *(const f32x4*)&wp[d];  // uniform addr -> LDS broadcast
#pragma unroll
      for (int e = 0; e < 4; ++e) {
        float he0 = h0[e], he1 = h1[e], ce0 = c0[e], ce1 = c1[e], we = w4[e];
        float r00 = __builtin_amdgcn_rcpf(ce0 * he0 + 1.0f);
        float r01 = __builtin_amdgcn_rcpf(ce0 * he1 + 1.0f);
        float r10 = __builtin_amdgcn_rcpf(ce1 * he0 + 1.0f);
        float r11 = __builtin_amdgcn_rcpf(ce1 * he1 + 1.0f);
        a00 = fmaf(we, r00, a00);
        a01 = fmaf(we, r01, a01);
        a10 = fmaf(we, r10, a10);
        a11 = fmaf(we, r11, a11);
      }
    }
    if (db < 3) __syncthreads();  // publish next buf; current buf free for db+2
  }

  const int gi0 = sbase + i0 + ty, gi1 = gi0 + 16;   // out rows (i, child)
  const int gj0 = j0 + tx, gj1 = gj0 + 16;           // out cols (j, head)
  const float mi0 = (1.0f - (float)mask[gi0]) * -1.0e8f;
  const float mi1 = (1.0f - (float)mask[gi1]) * -1.0e8f;
  const float mj0 = (1.0f - (float)mask[sbase + gj0]) * -1.0e8f;
  const float mj1 = (1.0f - (float)mask[sbase + gj1]) * -1.0e8f;
  out[(size_t)gi0 * SL + gj0] = S + a00 + mi0 + mj0;
  out[(size_t)gi0 * SL + gj1] = S + a01 + mi0 + mj1;
  out[(size_t)gi1 * SL + gj0] = S + a10 + mi1 + mj0;
  out[(size_t)gi1 * SL + gj1] = S + a11 + mi1 + mj1;
}

extern "C" void kernel_launch(void* const* d_in, const int* in_sizes, int n_in,
                              void* d_out, int out_size, void* d_ws, size_t ws_size,
                              hipStream_t stream) {
  (void)in_sizes; (void)n_in; (void)out_size; (void)ws_size;
  const float* enc = (const float*)d_in[0];   // (8,256,1024) fp32
  const int* mask = (const int*)d_in[1];      // (8,256) int32
  const float* Wh = (const float*)d_in[2];    // (256,1024) fp32
  const float* bh = (const float*)d_in[3];    // (256,) fp32
  const float* Wc = (const float*)d_in[4];    // (256,1024) fp32
  const float* wout = (const float*)d_in[5];  // (256,) fp32
  float* out = (float*)d_out;

  float* hc = (float*)d_ws;  // 4 MiB (2048 x 512 f32, exp-domain)

  projc_kernel<<<dim3(32, 8), 512, 0, stream>>>(enc, Wh, Wc, bh, hc);
  edge_kernel<<<dim3(8, 8, 8), 256, 0, stream>>>(hc, wout, mask, out);
}

// Round 5
// 97.375 us; speedup vs baseline: 1.4369x; 1.4369x over previous
//
#include <hip/hip_runtime.h>
#include <hip/hip_bf16.h>
#include <stdint.h>

// KGEdges round 18 — REVERT to R16 state (best measured: 99.44 us).
// R17 post-mortem: d-chunked dbuf edge regressed 4.5 -> 64 us (VALUBusy 18%,
// HBM 2% => pure stall). Runtime-indexed ldH[cur]/[nxt] LDS dbuf defeats
// compiler load/store disambiguation -> per-chunk vmcnt/lgkm drains expose full
// latency 4x and kill the ds_read pipeline; chunked 256B/row fetches lose MLP.
// Edge's compute phase is too short to hide staging under (T14-null regime).
// R16 structure (bulk stage, one barrier, one long unrolled trans loop) is
// near-optimal: 1024 v_rcp/thread x 4 cyc @ 2 waves/SIMD ~= 3.4 us floor, ~4.5 real.
// Budget at 99.44: ~85 us mandatory ws-poison fills (80% HBM peak = their own
// roofline, untouchable) + ~14.4 us kernels (projc ~3, edge ~4.5, ~2x dispatch
// overhead). Controllable slack ~3 us; R15/R16/R17 = -1.06/-0.18/-40 us.
// Semantics (R8-R16 green, absmax 0.015625): out[b,i,j] = sum_d w_out[d]*
// tanh(head[b,j,d]+child[b,i,d]) + mm_i + mm_j; head=enc@Wh^T+bh, child=enc@Wc^T;
// fp32 in / int32 mask / fp32 out. Exp-domain: sum w*tanh = S + sum(-2w)*
// rcp(Eh*Ec+1), E=exp2(K*x), K=2log2(e).

typedef __bf16 bf16_t;
typedef __attribute__((ext_vector_type(8))) __bf16 bf16x8;
typedef __attribute__((ext_vector_type(4))) float f32x4;
typedef __attribute__((ext_vector_type(4))) uint32_t u32x4;

#define SL 256
#define ENC 1024
#define NTOT 512
#define KSCALE 2.8853900817779268f  // 2*log2(e)
#define LSTR 260

__device__ __forceinline__ uint32_t bfpack(float a, float b) {  // 2x f32 -> packed bf16 (RNE)
  uint32_t ua = __float_as_uint(a); ua = ua + 0x7FFFu + ((ua >> 16) & 1u);
  uint32_t ub = __float_as_uint(b); ub = ub + 0x7FFFu + ((ub >> 16) & 1u);
  return (ua >> 16) | (ub & 0xFFFF0000u);
}

// ---- projc: fused convert+proj, register-prefetch pipeline, dbuf LDS, 8 waves.
// hc[s][0:256]=exp2(K*(enc@Wh^T+bh)) [Eh], hc[s][256:512]=exp2(K*enc@Wc^T) [Ec]
// 64x64 tile, BK=64 (16 iters, 1 barrier each), 8 waves each 1x2 sub-tile,
// 4x MFMA 16x16x32 bf16 per iter (bit-proven maps).
__global__ __launch_bounds__(512)
void projc_kernel(const float* __restrict__ enc, const float* __restrict__ Wh,
                  const float* __restrict__ Wc, const float* __restrict__ bh,
                  float* __restrict__ hc) {
  __shared__ bf16_t As[2][4096];   // 64 rows x 64 k, bf16 (8 KB each buf)
  __shared__ bf16_t Bs[2][4096];
  const int t = threadIdx.x;
  const int wv = t >> 6, lane = t & 63;
  const int m0 = blockIdx.x * 64;   // 32 blocks (2048 rows)
  const int n0 = blockIdx.y * 64;   // 8 blocks (512 cols of [head|child])
  const int srow = t >> 3;          // staging row 0..63
  const int sch = (t & 7) * 8;      // fp32 elem offset in row (0/8/.../56)
  const int mq = (wv & 3) * 16;     // wave's 16-row slice of the 64-row tile
  const int nq = (wv >> 2) * 32;    // wave's 32-col slice of the 64-col tile
  const int fr = lane & 15, kq = lane >> 4;

  f32x4 acc0 = {0.f, 0.f, 0.f, 0.f};
  f32x4 acc1 = acc0;

  const float* gA = enc + (size_t)(m0 + srow) * ENC + sch;
  const float* gW = ((n0 < 256) ? Wh + (size_t)(n0 + srow) * ENC
                                : Wc + (size_t)(n0 - 256 + srow) * ENC) + sch;

  // prologue: load k-tile 0 into registers (8 f32 per matrix per thread)
  f32x4 a0 = *(const f32x4*)(gA);
  f32x4 a1 = *(const f32x4*)(gA + 4);
  f32x4 w0 = *(const f32x4*)(gW);
  f32x4 w1 = *(const f32x4*)(gW + 4);

#pragma unroll 2
  for (int i = 0; i < 16; ++i) {
    const int buf = i & 1;
    // issue NEXT tile's loads first — they fly across pack+write+barrier+MFMA
    f32x4 na0, na1, nw0, nw1;
    if (i + 1 < 16) {
      const int k1 = (i + 1) * 64;
      na0 = *(const f32x4*)(gA + k1);
      na1 = *(const f32x4*)(gA + k1 + 4);
      nw0 = *(const f32x4*)(gW + k1);
      nw1 = *(const f32x4*)(gW + k1 + 4);
    } else {
      na0 = a0; na1 = a1; nw0 = w0; nw1 = w1;  // defined values on last iter
    }
    // pack current (vmcnt waits only on the older loads) and stage to LDS
    u32x4 Au = {bfpack(a0[0], a0[1]), bfpack(a0[2], a0[3]),
                bfpack(a1[0], a1[1]), bfpack(a1[2], a1[3])};
    u32x4 Wu = {bfpack(w0[0], w0[1]), bfpack(w0[2], w0[3]),
                bfpack(w1[0], w1[1]), bfpack(w1[2], w1[3])};
    *(u32x4*)&As[buf][t * 8] = Au;   // byte t*16: row srow, k-elems sch.. (linear)
    *(u32x4*)&Bs[buf][t * 8] = Wu;
    __syncthreads();  // publish buf; also fences write(i+1,~buf) from read(i-1,~buf)
    bf16x8 fa0 = *(const bf16x8*)&As[buf][(mq + fr) * 64 + kq * 8];        // k-chunk 0
    bf16x8 fa1 = *(const bf16x8*)&As[buf][(mq + fr) * 64 + 32 + kq * 8];  // k-chunk 1
    bf16x8 fb00 = *(const bf16x8*)&Bs[buf][(nq + fr) * 64 + kq * 8];
    bf16x8 fb01 = *(const bf16x8*)&Bs[buf][(nq + fr) * 64 + 32 + kq * 8];
    bf16x8 fb10 = *(const bf16x8*)&Bs[buf][(nq + 16 + fr) * 64 + kq * 8];
    bf16x8 fb11 = *(const bf16x8*)&Bs[buf][(nq + 16 + fr) * 64 + 32 + kq * 8];
    // k-chunk 0 then k-chunk 1: identical accumulation order to BK=32 version
    acc0 = __builtin_amdgcn_mfma_f32_16x16x32_bf16(fa0, fb00, acc0, 0, 0, 0);
    acc1 = __builtin_amdgcn_mfma_f32_16x16x32_bf16(fa0, fb10, acc1, 0, 0, 0);
    acc0 = __builtin_amdgcn_mfma_f32_16x16x32_bf16(fa1, fb01, acc0, 0, 0, 0);
    acc1 = __builtin_amdgcn_mfma_f32_16x16x32_bf16(fa1, fb11, acc1, 0, 0, 0);
    a0 = na0; a1 = na1; w0 = nw0; w1 = nw1;  // rotate prefetch regs
  }
  // C/D: col=lane&15, row=(lane>>4)*4+r  (bit-proven)
  const int colA = n0 + nq + fr;
  const int colB = colA + 16;
  const float biasA = (colA < 256) ? bh[colA] : 0.0f;
  const float biasB = (colB < 256) ? bh[colB] : 0.0f;
#pragma unroll
  for (int r = 0; r < 4; ++r) {
    int row = m0 + mq + kq * 4 + r;
    hc[(size_t)row * NTOT + colA] = __builtin_amdgcn_exp2f(KSCALE * (acc0[r] + biasA));
    hc[(size_t)row * NTOT + colB] = __builtin_amdgcn_exp2f(KSCALE * (acc1[r] + biasB));
  }
}

// ---- edge: out[b,i,j] = S + sum_d (-2w[d])*rcp(Eh[j,d]*Ec[i,d]+1) + mm_i + mm_j ----
// R16 version (proven): bulk stage, one barrier, S via wave shfl_xor folded under it.
__global__ __launch_bounds__(256)
void edge_kernel(const float* __restrict__ hc, const float* __restrict__ wout,
                 const int* __restrict__ mask, float* __restrict__ out) {
  __shared__ float ldH[32 * LSTR];
  __shared__ float ldC[32 * LSTR];
  __shared__ float wS[256];
  __shared__ float red[4];
  const int t = threadIdx.x;
  const int lane = t & 63, wv = t >> 6;
  const int b = blockIdx.z;
  const int i0 = blockIdx.y * 32;
  const int j0 = blockIdx.x * 32;
  const int sbase = b * SL;

  float w = wout[t];
  wS[t] = -2.0f * w;
  float wsum = w;
#pragma unroll
  for (int off = 32; off; off >>= 1) wsum += __shfl_xor(wsum, off);
  if (lane == 0) red[wv] = wsum;

  for (int u = t; u < 32 * 64; u += 256) {
    int row = u >> 6;
    int c4 = (u & 63) << 2;
    f32x4 hv = *(const f32x4*)&hc[(size_t)(sbase + j0 + row) * NTOT + c4];        // Eh(j)
    f32x4 cv = *(const f32x4*)&hc[(size_t)(sbase + i0 + row) * NTOT + 256 + c4];  // Ec(i)
    *(f32x4*)&ldH[row * LSTR + c4] = hv;
    *(f32x4*)&ldC[row * LSTR + c4] = cv;
  }
  __syncthreads();  // covers staging AND the red[] partials
  const float S = (red[0] + red[1]) + (red[2] + red[3]);

  const int tx = t & 15, ty = t >> 4;
  const float* hp0 = &ldH[tx * LSTR];
  const float* hp1 = &ldH[(tx + 16) * LSTR];
  const float* cp0 = &ldC[ty * LSTR];
  const float* cp1 = &ldC[(ty + 16) * LSTR];
  float a00 = 0.f, a01 = 0.f, a10 = 0.f, a11 = 0.f;

#pragma unroll 8
  for (int d = 0; d < 256; d += 4) {
    f32x4 h0 = *(const f32x4*)&hp0[d];
    f32x4 h1 = *(const f32x4*)&hp1[d];
    f32x4 c0 = *(const f32x4*)&cp0[d];
    f32x4 c1 = *(const f32x4*)&cp1[d];
    f32x4 w4 = *(const f32x4*)&wS[d];  // uniform addr -> LDS broadcast
#pragma unroll
    for (int e = 0; e < 4; ++e) {
      float he0 = h0[e], he1 = h1[e], ce0 = c0[e], ce1 = c1[e], we = w4[e];
      float r00 = __builtin_amdgcn_rcpf(ce0 * he0 + 1.0f);
      float r01 = __builtin_amdgcn_rcpf(ce0 * he1 + 1.0f);
      float r10 = __builtin_amdgcn_rcpf(ce1 * he0 + 1.0f);
      float r11 = __builtin_amdgcn_rcpf(ce1 * he1 + 1.0f);
      a00 = fmaf(we, r00, a00);
      a01 = fmaf(we, r01, a01);
      a10 = fmaf(we, r10, a10);
      a11 = fmaf(we, r11, a11);
    }
  }

  const int gi0 = sbase + i0 + ty, gi1 = gi0 + 16;   // out rows (i, child)
  const int gj0 = j0 + tx, gj1 = gj0 + 16;           // out cols (j, head)
  const float mi0 = (1.0f - (float)mask[gi0]) * -1.0e8f;
  const float mi1 = (1.0f - (float)mask[gi1]) * -1.0e8f;
  const float mj0 = (1.0f - (float)mask[sbase + gj0]) * -1.0e8f;
  const float mj1 = (1.0f - (float)mask[sbase + gj1]) * -1.0e8f;
  out[(size_t)gi0 * SL + gj0] = S + a00 + mi0 + mj0;
  out[(size_t)gi0 * SL + gj1] = S + a01 + mi0 + mj1;
  out[(size_t)gi1 * SL + gj0] = S + a10 + mi1 + mj0;
  out[(size_t)gi1 * SL + gj1] = S + a11 + mi1 + mj1;
}

extern "C" void kernel_launch(void* const* d_in, const int* in_sizes, int n_in,
                              void* d_out, int out_size, void* d_ws, size_t ws_size,
                              hipStream_t stream) {
  (void)in_sizes; (void)n_in; (void)out_size; (void)ws_size;
  const float* enc = (const float*)d_in[0];   // (8,256,1024) fp32
  const int* mask = (const int*)d_in[1];      // (8,256) int32
  const float* Wh = (const float*)d_in[2];    // (256,1024) fp32
  const float* bh = (const float*)d_in[3];    // (256,) fp32
  const float* Wc = (const float*)d_in[4];    // (256,1024) fp32
  const float* wout = (const float*)d_in[5];  // (256,) fp32
  float* out = (float*)d_out;

  float* hc = (float*)d_ws;  // 4 MiB (2048 x 512 f32, exp-domain)

  projc_kernel<<<dim3(32, 8), 512, 0, stream>>>(enc, Wh, Wc, bh, hc);
  edge_kernel<<<dim3(8, 8, 8), 256, 0, stream>>>(hc, wout, mask, out);
}